// Round 5
// baseline (260.002 us; speedup 1.0000x reference)
//
#include <hip/hip_runtime.h>

#define NN 20000      // nodes
#define FIN 256
#define D1 1024       // H1*C1 = 8*128
#define NH 8
#define C2 128
#define CAP 64        // padded CSR bucket capacity (max degree ~35 incl. self-loop)

typedef unsigned short u16;
typedef unsigned char u8;
typedef __attribute__((ext_vector_type(8))) short bf16x8;
typedef __attribute__((ext_vector_type(4))) float f32x4;
typedef __attribute__((ext_vector_type(2))) float f32x2;

// ---------- bf16 helpers ----------
__device__ __forceinline__ float bf2f(u16 u) {
    return __uint_as_float(((unsigned int)u) << 16);
}
__device__ __forceinline__ u16 f2bf(float f) {
    unsigned int u = __float_as_uint(f);
    u += 0x7FFFu + ((u >> 16) & 1u);   // round-to-nearest-even
    return (u16)(u >> 16);
}
// ---------- fp8 e4m3 (OCP) helpers via HW converts ----------
__device__ __forceinline__ u8 f2fp8(float v) {
    int q = __builtin_amdgcn_cvt_pk_fp8_f32(v, v, 0, false);
    return (u8)(q & 0xFF);
}

// butterfly reductions: every lane ends with the result
__device__ __forceinline__ float bred_max(float v) {
    #pragma unroll
    for (int o = 32; o > 0; o >>= 1) v = fmaxf(v, __shfl_xor(v, o, 64));
    return v;
}
__device__ __forceinline__ float bred_sum(float v) {
    #pragma unroll
    for (int o = 32; o > 0; o >>= 1) v += __shfl_xor(v, o, 64);
    return v;
}

// async global->LDS, 16B per lane (global_load_lds_dwordx4)
typedef const __attribute__((address_space(1))) unsigned int* as1_u32p;
typedef __attribute__((address_space(3))) unsigned int* as3_u32p;
__device__ __forceinline__ void gload_lds16(const void* g, void* l) {
    __builtin_amdgcn_global_load_lds((as1_u32p)g, (as3_u32p)l, 16, 0, 0);
}

// ---------- fused prep: cast x->bf16 | transpose W1/W2 | CSR fill ----------
// cnt is zeroed by hipMemsetAsync BEFORE this kernel, so the fill part can
// run concurrently with the cast/transpose blocks (no intra-kernel ordering
// needed: they touch disjoint data).
// Block ranges: [0,5000) cast, [5000,5256) W1t, [5256,5384) W2t,
// [5384, 5384+ceil((E+NN)/256)) edge fill.
__global__ __launch_bounds__(256) void prep_kernel(const float* __restrict__ x,
                                                   u16* __restrict__ xb,
                                                   const float* __restrict__ W1,
                                                   u16* __restrict__ w1t,
                                                   const float* __restrict__ W2,
                                                   u16* __restrict__ w2t,
                                                   const int* __restrict__ ei,
                                                   int E,
                                                   int* __restrict__ cnt,
                                                   int* __restrict__ csr) {
    __shared__ float tile[32][33];
    const int b = blockIdx.x, tid = threadIdx.x;
    if (b < 5000) {
        int i = (b * 256 + tid) * 4;
        if (i < NN * FIN) {
            float4 v = *(const float4*)(x + i);
            ushort4 o;
            o.x = f2bf(v.x); o.y = f2bf(v.y); o.z = f2bf(v.z); o.w = f2bf(v.w);
            *(ushort4*)(xb + i) = o;
        }
        return;
    }
    if (b < 5384) {
        const float* in; u16* out; int R, C, bx, by;
        if (b < 5256) {
            int q = b - 5000;                 // W1: [FIN x D1] -> [D1 x FIN]
            in = W1; out = w1t; R = FIN; C = D1;
            bx = (q & 31) * 32; by = (q >> 5) * 32;
        } else {
            int q = b - 5256;                 // W2: [D1 x C2] -> [C2 x D1]
            in = W2; out = w2t; R = D1; C = C2;
            bx = (q & 3) * 32; by = (q >> 2) * 32;
        }
        int tx = tid & 31, ty = tid >> 5;     // 32x8
        #pragma unroll
        for (int i = 0; i < 32; i += 8)
            tile[ty + i][tx] = in[(size_t)(by + ty + i) * C + bx + tx];
        __syncthreads();
        #pragma unroll
        for (int i = 0; i < 32; i += 8)
            out[(size_t)(bx + ty + i) * R + by + tx] = f2bf(tile[tx][ty + i]);
        return;
    }
    // ---- padded-bucket CSR fill (self-loops appended) ----
    int j = (b - 5384) * 256 + tid;
    if (j >= E + NN) return;
    int s, d;
    if (j < E) { s = ei[j]; d = ei[E + j]; }
    else { s = j - E; d = j - E; }
    int pos = atomicAdd(&cnt[d], 1);
    if (pos >= CAP) return;   // safety net (never expected)
    csr[d * CAP + pos] = s;
}

// ---------- bf16 MFMA GEMM, 2-phase double-buffered (T3-minimum) ----------
// C[MxN] = A[MxK] * Bt[NxK]^T.  Per K-step: issue next tile's
// global_load_lds into buf^1, then ds_read+MFMA on buf, then ONE
// __syncthreads. Fused per-head attention-dot epilogue.
// OMODE 1: bf16 C out (layer 2); OMODE 2: fp8 e4m3 C out (layer 1).
#define G_STAGE(BUF, K0)                                                   \
    {                                                                      \
        _Pragma("unroll")                                                  \
        for (int i = 0; i < BM / 64; i++) {                                \
            int c = tid + i * 256;                                         \
            int r = c >> 2, ko = (c & 3) * 8;                              \
            int gr = row0 + r; if (gr >= M) gr = M - 1;                    \
            gload_lds16(A + (size_t)gr * K + (K0) + ko,                    \
                        &ldsA[BUF][c * 8]);                                \
        }                                                                  \
        _Pragma("unroll")                                                  \
        for (int i = 0; i < 2; i++) {                                      \
            int c = tid + i * 256;                                         \
            int n = c >> 2, ko = (c & 3) * 8;                              \
            gload_lds16(Bt + (size_t)(col0 + n) * K + (K0) + ko,           \
                        &ldsB[BUF][c * 8]);                                \
        }                                                                  \
    }

template <int BM, int OMODE>
__global__ __launch_bounds__(256) void gemm_mfma(const u16* __restrict__ A,
                                                 const u16* __restrict__ Bt,
                                                 void* __restrict__ C,
                                                 const float* __restrict__ attS,
                                                 const float* __restrict__ attD,
                                                 float* __restrict__ as_out,
                                                 float* __restrict__ ad_out,
                                                 int NHo,
                                                 int M, int N, int K) {
    constexpr int TM = BM / 32;            // 16-tiles per wave along m
    __shared__ u16 ldsA[2][BM * 32];
    __shared__ u16 ldsB[2][128 * 32];
    __shared__ float asb[BM], adb[BM];
    const int tid = threadIdx.x;
    const int lane = tid & 63, w = tid >> 6;
    const int wr = w >> 1, wc = w & 1;
    const int row0 = blockIdx.x * BM, col0 = blockIdx.y * 128;
    const int head = blockIdx.y;
    const int l15 = lane & 15, quad = lane >> 4;

    for (int t = tid; t < BM; t += 256) { asb[t] = 0.f; adb[t] = 0.f; }

    f32x4 acc[TM][4];
    #pragma unroll
    for (int i = 0; i < TM; i++)
        #pragma unroll
        for (int j = 0; j < 4; j++)
            acc[i][j] = (f32x4){0.f, 0.f, 0.f, 0.f};

    G_STAGE(0, 0)
    __syncthreads();
    int cur = 0;
    for (int k0 = 0; k0 < K; k0 += 32) {
        if (k0 + 32 < K) {
            G_STAGE(cur ^ 1, k0 + 32)              // prefetch next K-tile
            __builtin_amdgcn_sched_barrier(0);     // keep issue above compute
        }
        bf16x8 af[TM], bfr[4];
        #pragma unroll
        for (int i = 0; i < TM; i++) {
            int m = wr * (BM / 2) + i * 16 + l15;
            af[i] = *(const bf16x8*)(&ldsA[cur][m * 32 + quad * 8]);
        }
        #pragma unroll
        for (int j = 0; j < 4; j++) {
            int n = wc * 64 + j * 16 + l15;
            bfr[j] = *(const bf16x8*)(&ldsB[cur][n * 32 + quad * 8]);
        }
        #pragma unroll
        for (int i = 0; i < TM; i++)
            #pragma unroll
            for (int j = 0; j < 4; j++)
                acc[i][j] = __builtin_amdgcn_mfma_f32_16x16x32_bf16(af[i], bfr[j], acc[i][j], 0, 0, 0);
        __syncthreads();                           // buf^1 staged + all reads done
        cur ^= 1;
    }
    // ---- C write (fp8 for layer1, bf16 for layer2) ----
    #pragma unroll
    for (int i = 0; i < TM; i++) {
        #pragma unroll
        for (int j = 0; j < 4; j++) {
            #pragma unroll
            for (int r = 0; r < 4; r++) {
                int row = row0 + wr * (BM / 2) + i * 16 + quad * 4 + r;
                int col = col0 + wc * 64 + j * 16 + l15;
                if (row < M) {
                    float v = acc[i][j][r];
                    if (OMODE == 1)
                        ((u16*)C)[(size_t)row * N + col] = f2bf(v);
                    else
                        ((u8*)C)[(size_t)row * N + col] = f2fp8(v);
                }
            }
        }
    }
    // ---- fused per-row attention dots for this head ----
    float attS_r[4], attD_r[4];
    #pragma unroll
    for (int j = 0; j < 4; j++) {
        int col = wc * 64 + j * 16 + l15;
        attS_r[j] = attS[head * 128 + col];
        attD_r[j] = attD[head * 128 + col];
    }
    #pragma unroll
    for (int i = 0; i < TM; i++) {
        #pragma unroll
        for (int r = 0; r < 4; r++) {
            float ps = 0.f, pd = 0.f;
            #pragma unroll
            for (int j = 0; j < 4; j++) {
                float v = acc[i][j][r];
                ps = fmaf(v, attS_r[j], ps);
                pd = fmaf(v, attD_r[j], pd);
            }
            #pragma unroll
            for (int o = 1; o < 16; o <<= 1) {
                ps += __shfl_xor(ps, o, 64);
                pd += __shfl_xor(pd, o, 64);
            }
            if (l15 == 0) {
                int row = wr * (BM / 2) + i * 16 + quad * 4 + r;
                atomicAdd(&asb[row], ps);
                atomicAdd(&adb[row], pd);
            }
        }
    }
    __syncthreads();
    for (int t = tid; t < BM; t += 256) {
        int row = row0 + t;
        if (row < M) {
            as_out[(size_t)row * NHo + head] = asb[t];
            ad_out[(size_t)row * NHo + head] = adb[t];
        }
    }
}

// ---------- layer-1 softmax-aggregate + ELU, CHANNEL-SLICED ----------
// 8 slices x 128 channels; slice s == head s exactly. Wave handles
// (dst, slice): 2 fp8 ch/lane, one coalesced 128B load per edge.
// Slice is pinned to XCD via blockIdx.x & 7 (consecutive blocks
// round-robin XCDs), so each XCD's gather working set is NN*128B =
// 2.56MB < 4MB L2 -> edge gathers become L2 HITS (R4: 157MB L2-miss
// fetch for a 20.5MB array = per-XCD L2 thrash, the measured wall).
// Slice==head makes the edge weight WAVE-UNIFORM: one exp per edge
// computed in setup (agg2's structure), broadcast via readlane -- kills
// R4's 8-per-group as1 loads and per-lane leaky/exp in PROC.
#define A1_FETCH8(E0, Q)                                                      \
    {                                                                         \
        _Pragma("unroll")                                                     \
        for (int u = 0; u < 8; u++) {                                         \
            int s = __builtin_amdgcn_readlane(idx, (E0) + u);                 \
            s = s < 0 ? 0 : (s > NN - 1 ? NN - 1 : s);   /* SALU clamp */     \
            Q[u] = *(const u16*)(h1q + (size_t)s * D1 + coff);                \
        }                                                                     \
        __builtin_amdgcn_sched_barrier(0);                                    \
    }
#define A1_PROC8(E0, Q)                                                       \
    {                                                                         \
        _Pragma("unroll")                                                     \
        for (int u = 0; u < 8; u++) {                                         \
            int e = (E0) + u;                                                 \
            float pp = (e < deg) ? __uint_as_float(__builtin_amdgcn_readlane( \
                                       __float_as_uint(pl), e))               \
                                 : 0.f;                                       \
            den += pp;                                                        \
            f32x2 pv2 = {pp, pp};                                             \
            acc += pv2 * __builtin_amdgcn_cvt_pk_f32_fp8((unsigned int)(Q)[u],\
                                                         false);              \
        }                                                                     \
    }

__global__ __launch_bounds__(256) void agg1_kernel(const u8* __restrict__ h1q,
                                                   const float* __restrict__ as1,
                                                   const float* __restrict__ ad1,
                                                   const int* __restrict__ cnt,
                                                   const int* __restrict__ csr,
                                                   const float* __restrict__ bias1,
                                                   u16* __restrict__ x2) {
    const int tid = threadIdx.x;
    const int lane = tid & 63;
    const int sl = blockIdx.x & 7;                  // slice == head, XCD-pinned
    const int dst = ((blockIdx.x >> 3) << 2) + (tid >> 6);
    const int base = dst * CAP;
    const int coff = sl * 128 + lane * 2;           // 2 channels per lane

    int idx = csr[base + lane];                     // unclamped; || with cnt load
    const int deg = __builtin_amdgcn_readfirstlane(max(1, min(cnt[dst], CAP)));
    const float adv = ad1[dst * NH + sl];
    int idxc = idx < 0 ? 0 : (idx > NN - 1 ? NN - 1 : idx);
    float ev = as1[idxc * NH + sl] + adv;           // 640KB L2-resident table
    ev = ev > 0.f ? ev : 0.2f * ev;                 // LeakyReLU(0.2)
    float pl = __expf(ev);                          // lane e holds w(edge e)

    f32x2 acc = {0.f, 0.f};
    float den = 0.f;

    const int nit = (deg + 7) >> 3;                 // groups of 8, ping-pong
    u16 qa[8], qb[8];
    A1_FETCH8(0, qa)
    int g = 0;
    for (; g + 2 < nit; g += 2) {
        A1_FETCH8((g + 1) * 8, qb)
        A1_PROC8(g * 8, qa)
        A1_FETCH8((g + 2) * 8, qa)
        A1_PROC8((g + 1) * 8, qb)
    }
    if (g + 1 < nit) {
        A1_FETCH8((g + 1) * 8, qb)
        A1_PROC8(g * 8, qa)
        A1_PROC8((g + 1) * 8, qb)
    } else {
        A1_PROC8(g * 8, qa)
    }

    float inv = 1.f / (den + 1e-16f);
    float2 bv = *(const float2*)(bias1 + coff);
    float a0 = acc[0] * inv + bv.x;
    float a1 = acc[1] * inv + bv.y;
    a0 = a0 > 0.f ? a0 : (__expf(a0) - 1.f);        // ELU (abs err ~1e-7, tol .03)
    a1 = a1 > 0.f ? a1 : (__expf(a1) - 1.f);
    unsigned int ow = (unsigned int)f2bf(a0) | ((unsigned int)f2bf(a1) << 16);
    *(unsigned int*)(x2 + (size_t)dst * D1 + coff) = ow;
}

// ---------- layer-2 softmax-aggregate + log_softmax (inline edge weights) ----------
// ONE WAVE per dst; GROUP=8 depth-2 ping-pong + parallel setup loads.
#define A2_FETCH8(E0, Q)                                                      \
    {                                                                         \
        _Pragma("unroll")                                                     \
        for (int u = 0; u < 8; u++) {                                         \
            int s = __builtin_amdgcn_readlane(idx, (E0) + u);                 \
            s = s < 0 ? 0 : (s > NN - 1 ? NN - 1 : s);                        \
            Q[u] = *(const unsigned int*)(h2 + (size_t)s * C2 + lane2);       \
        }                                                                     \
        __builtin_amdgcn_sched_barrier(0);                                    \
    }
#define A2_PROC8(E0, Q)                                                       \
    {                                                                         \
        _Pragma("unroll")                                                     \
        for (int u = 0; u < 8; u++) {                                         \
            int e = (E0) + u;                                                 \
            float pp = (e < deg) ? __uint_as_float(__builtin_amdgcn_readlane( \
                                       __float_as_uint(pl), e))               \
                                 : 0.f;                                       \
            den += pp;                                                        \
            f32x2 pv2 = {pp, pp};                                             \
            f32x2 f = {__uint_as_float((Q)[u] << 16),                         \
                       __uint_as_float((Q)[u] & 0xFFFF0000u)};                \
            acc += pv2 * f;                                                   \
        }                                                                     \
    }

__global__ __launch_bounds__(256) void agg2_kernel(const u16* __restrict__ h2,
                                                   const float* __restrict__ as2,
                                                   const float* __restrict__ ad2,
                                                   const int* __restrict__ cnt,
                                                   const int* __restrict__ csr,
                                                   const float* __restrict__ bias2,
                                                   float* __restrict__ out) {
    const int tid = threadIdx.x;
    const int lane = tid & 63;
    const int dst = (blockIdx.x << 2) + (tid >> 6);
    const int base = dst * CAP;
    const int lane2 = lane * 2;

    int idx = csr[base + lane];                 // unclamped: || with cnt load
    const int deg = __builtin_amdgcn_readfirstlane(max(1, min(cnt[dst], CAP)));
    const float adv = ad2[dst];
    int idxc = idx < 0 ? 0 : (idx > NN - 1 ? NN - 1 : idx);
    float ev = as2[idxc] + adv;                 // random 4B within 80 KB (L2-hit)
    ev = ev > 0.f ? ev : 0.2f * ev;
    float pl = __expf(ev);                      // finite for any in-range row

    f32x2 acc = {0.f, 0.f};
    float den = 0.f;

    const int nit = (deg + 7) >> 3;
    unsigned int qa[8], qb[8];
    A2_FETCH8(0, qa)
    int g = 0;
    for (; g + 2 < nit; g += 2) {
        A2_FETCH8((g + 1) * 8, qb)
        A2_PROC8(g * 8, qa)
        A2_FETCH8((g + 2) * 8, qa)
        A2_PROC8((g + 1) * 8, qb)
    }
    if (g + 1 < nit) {
        A2_FETCH8((g + 1) * 8, qb)
        A2_PROC8(g * 8, qa)
        A2_PROC8((g + 1) * 8, qb)
    } else {
        A2_PROC8(g * 8, qa)
    }

    float inv = 1.f / (den + 1e-16f);
    float l0 = acc[0] * inv + bias2[lane2];
    float l1 = acc[1] * inv + bias2[lane2 + 1];
    // log_softmax over the wave's 128 channels
    float m = bred_max(fmaxf(l0, l1));
    float ex = bred_sum(__expf(l0 - m) + __expf(l1 - m));
    float lse = m + __logf(ex);
    float2 ov = {l0 - lse, l1 - lse};
    *(float2*)(out + (size_t)dst * C2 + lane2) = ov;
}

extern "C" void kernel_launch(void* const* d_in, const int* in_sizes, int n_in,
                              void* d_out, int out_size, void* d_ws, size_t ws_size,
                              hipStream_t stream) {
    const float* x        = (const float*)d_in[0];
    const int*   ei       = (const int*)d_in[1];
    const float* W1       = (const float*)d_in[2];
    const float* att_src1 = (const float*)d_in[3];
    const float* att_dst1 = (const float*)d_in[4];
    const float* bias1    = (const float*)d_in[5];
    const float* W2       = (const float*)d_in[6];
    const float* att_src2 = (const float*)d_in[7];
    const float* att_dst2 = (const float*)d_in[8];
    const float* bias2    = (const float*)d_in[9];
    float* out = (float*)d_out;
    const int E = in_sizes[1] / 2;

    char* ws = (char*)d_ws;
    size_t off = 0;
    auto alloc = [&](size_t b) {
        void* p = ws + off;
        off += (b + 255) & ~(size_t)255;
        return p;
    };
    u8*  h1q  = (u8*)alloc((size_t)NN * D1);
    u16* x2   = (u16*)alloc((size_t)NN * D1 * 2);
    u16* h2   = (u16*)alloc((size_t)NN * C2 * 2);
    u16* xb   = (u16*)alloc((size_t)NN * FIN * 2);
    u16* w1t  = (u16*)alloc((size_t)D1 * FIN * 2);
    u16* w2t  = (u16*)alloc((size_t)C2 * D1 * 2);
    float* as1 = (float*)alloc((size_t)NN * NH * 4);
    float* ad1 = (float*)alloc((size_t)NN * NH * 4);
    float* as2 = (float*)alloc((size_t)NN * 4);
    float* ad2 = (float*)alloc((size_t)NN * 4);
    int* cnt  = (int*)alloc((size_t)NN * 4);
    int* csr  = (int*)alloc((size_t)NN * CAP * 4);

    // zero cnt up front; fused prep then casts x, transposes W1/W2 AND
    // fills the CSR buckets (fill overlaps the BW-heavy cast blocks)
    hipMemsetAsync(cnt, 0, (size_t)NN * 4, stream);
    const int FILL_BLOCKS = (E + NN + 255) / 256;
    prep_kernel<<<5384 + FILL_BLOCKS, 256, 0, stream>>>(x, xb, W1, w1t, W2, w2t,
                                                        ei, E, cnt, csr);

    // layer 1 GEMM: h1q fp8 + fused per-head as1/ad1
    gemm_mfma<128, 2><<<dim3((NN + 127) / 128, D1 / 128), 256, 0, stream>>>(
        xb, w1t, h1q, att_src1, att_dst1, as1, ad1, NH, NN, D1, FIN);
    // channel-sliced aggregate: 8 slices x 5000 dst-groups
    agg1_kernel<<<((NN + 3) / 4) * 8, 256, 0, stream>>>(h1q, as1, ad1, cnt, csr,
                                                        bias1, x2);
    // layer 2 GEMM: h2 bf16 + fused as2/ad2
    gemm_mfma<64, 1><<<dim3((NN + 63) / 64, C2 / 128), 256, 0, stream>>>(
        x2, w2t, h2, att_src2, att_dst2, as2, ad2, 1, NN, C2, D1);
    agg2_kernel<<<(NN + 3) / 4, 256, 0, stream>>>(h2, as2, ad2, cnt, csr, bias2, out);
}

// Round 6
// 258.792 us; speedup vs baseline: 1.0047x; 1.0047x over previous
//
#include <hip/hip_runtime.h>

#define NN 20000      // nodes
#define FIN 256
#define D1 1024       // H1*C1 = 8*128
#define NH 8
#define C2 128
#define CAP 64        // padded CSR bucket capacity (max degree ~35 incl. self-loop)

typedef unsigned short u16;
typedef unsigned char u8;
typedef __attribute__((ext_vector_type(8))) short bf16x8;
typedef __attribute__((ext_vector_type(4))) float f32x4;
typedef __attribute__((ext_vector_type(2))) float f32x2;

// ---------- bf16 helpers ----------
__device__ __forceinline__ float bf2f(u16 u) {
    return __uint_as_float(((unsigned int)u) << 16);
}
__device__ __forceinline__ u16 f2bf(float f) {
    unsigned int u = __float_as_uint(f);
    u += 0x7FFFu + ((u >> 16) & 1u);   // round-to-nearest-even
    return (u16)(u >> 16);
}
// ---------- fp8 e4m3 (OCP) helpers via HW converts ----------
__device__ __forceinline__ u8 f2fp8(float v) {
    int q = __builtin_amdgcn_cvt_pk_fp8_f32(v, v, 0, false);
    return (u8)(q & 0xFF);
}

// butterfly reductions: every lane ends with the result
__device__ __forceinline__ float bred_max(float v) {
    #pragma unroll
    for (int o = 32; o > 0; o >>= 1) v = fmaxf(v, __shfl_xor(v, o, 64));
    return v;
}
__device__ __forceinline__ float bred_sum(float v) {
    #pragma unroll
    for (int o = 32; o > 0; o >>= 1) v += __shfl_xor(v, o, 64);
    return v;
}

// async global->LDS, 16B per lane (global_load_lds_dwordx4)
typedef const __attribute__((address_space(1))) unsigned int* as1_u32p;
typedef __attribute__((address_space(3))) unsigned int* as3_u32p;
__device__ __forceinline__ void gload_lds16(const void* g, void* l) {
    __builtin_amdgcn_global_load_lds((as1_u32p)g, (as3_u32p)l, 16, 0, 0);
}

// ---------- fused prep: cast x->bf16 | transpose W1/W2 | CSR fill ----------
// cnt is zeroed by hipMemsetAsync BEFORE this kernel, so the fill part can
// run concurrently with the cast/transpose blocks (disjoint data).
// Block ranges: [0,5000) cast, [5000,5256) W1t, [5256,5384) W2t,
// [5384, 5384+ceil((E+NN)/256)) edge fill.
__global__ __launch_bounds__(256) void prep_kernel(const float* __restrict__ x,
                                                   u16* __restrict__ xb,
                                                   const float* __restrict__ W1,
                                                   u16* __restrict__ w1t,
                                                   const float* __restrict__ W2,
                                                   u16* __restrict__ w2t,
                                                   const int* __restrict__ ei,
                                                   int E,
                                                   int* __restrict__ cnt,
                                                   int* __restrict__ csr) {
    __shared__ float tile[32][33];
    const int b = blockIdx.x, tid = threadIdx.x;
    if (b < 5000) {
        int i = (b * 256 + tid) * 4;
        if (i < NN * FIN) {
            float4 v = *(const float4*)(x + i);
            ushort4 o;
            o.x = f2bf(v.x); o.y = f2bf(v.y); o.z = f2bf(v.z); o.w = f2bf(v.w);
            *(ushort4*)(xb + i) = o;
        }
        return;
    }
    if (b < 5384) {
        const float* in; u16* out; int R, C, bx, by;
        if (b < 5256) {
            int q = b - 5000;                 // W1: [FIN x D1] -> [D1 x FIN]
            in = W1; out = w1t; R = FIN; C = D1;
            bx = (q & 31) * 32; by = (q >> 5) * 32;
        } else {
            int q = b - 5256;                 // W2: [D1 x C2] -> [C2 x D1]
            in = W2; out = w2t; R = D1; C = C2;
            bx = (q & 3) * 32; by = (q >> 2) * 32;
        }
        int tx = tid & 31, ty = tid >> 5;     // 32x8
        #pragma unroll
        for (int i = 0; i < 32; i += 8)
            tile[ty + i][tx] = in[(size_t)(by + ty + i) * C + bx + tx];
        __syncthreads();
        #pragma unroll
        for (int i = 0; i < 32; i += 8)
            out[(size_t)(bx + ty + i) * R + by + tx] = f2bf(tile[tx][ty + i]);
        return;
    }
    // ---- padded-bucket CSR fill (self-loops appended) ----
    int j = (b - 5384) * 256 + tid;
    if (j >= E + NN) return;
    int s, d;
    if (j < E) { s = ei[j]; d = ei[E + j]; }
    else { s = j - E; d = j - E; }
    int pos = atomicAdd(&cnt[d], 1);
    if (pos >= CAP) return;   // safety net (never expected)
    csr[d * CAP + pos] = s;
}

// ---------- bf16 MFMA GEMM, 2-phase double-buffered (T3-minimum) ----------
// C[MxN] = A[MxK] * Bt[NxK]^T.  Per K-step: issue next tile's
// global_load_lds into buf^1, then ds_read+MFMA on buf, then ONE
// __syncthreads. Fused per-head attention-dot epilogue.
// OMODE 1: bf16 C out (layer 2); OMODE 2: fp8 e4m3 C out (layer 1).
#define G_STAGE(BUF, K0)                                                   \
    {                                                                      \
        _Pragma("unroll")                                                  \
        for (int i = 0; i < BM / 64; i++) {                                \
            int c = tid + i * 256;                                         \
            int r = c >> 2, ko = (c & 3) * 8;                              \
            int gr = row0 + r; if (gr >= M) gr = M - 1;                    \
            gload_lds16(A + (size_t)gr * K + (K0) + ko,                    \
                        &ldsA[BUF][c * 8]);                                \
        }                                                                  \
        _Pragma("unroll")                                                  \
        for (int i = 0; i < 2; i++) {                                      \
            int c = tid + i * 256;                                         \
            int n = c >> 2, ko = (c & 3) * 8;                              \
            gload_lds16(Bt + (size_t)(col0 + n) * K + (K0) + ko,           \
                        &ldsB[BUF][c * 8]);                                \
        }                                                                  \
    }

template <int BM, int OMODE>
__global__ __launch_bounds__(256) void gemm_mfma(const u16* __restrict__ A,
                                                 const u16* __restrict__ Bt,
                                                 void* __restrict__ C,
                                                 const float* __restrict__ attS,
                                                 const float* __restrict__ attD,
                                                 float* __restrict__ as_out,
                                                 float* __restrict__ ad_out,
                                                 int NHo,
                                                 int M, int N, int K) {
    constexpr int TM = BM / 32;            // 16-tiles per wave along m
    __shared__ u16 ldsA[2][BM * 32];
    __shared__ u16 ldsB[2][128 * 32];
    __shared__ float asb[BM], adb[BM];
    const int tid = threadIdx.x;
    const int lane = tid & 63, w = tid >> 6;
    const int wr = w >> 1, wc = w & 1;
    const int row0 = blockIdx.x * BM, col0 = blockIdx.y * 128;
    const int head = blockIdx.y;
    const int l15 = lane & 15, quad = lane >> 4;

    for (int t = tid; t < BM; t += 256) { asb[t] = 0.f; adb[t] = 0.f; }

    f32x4 acc[TM][4];
    #pragma unroll
    for (int i = 0; i < TM; i++)
        #pragma unroll
        for (int j = 0; j < 4; j++)
            acc[i][j] = (f32x4){0.f, 0.f, 0.f, 0.f};

    G_STAGE(0, 0)
    __syncthreads();
    int cur = 0;
    for (int k0 = 0; k0 < K; k0 += 32) {
        if (k0 + 32 < K) {
            G_STAGE(cur ^ 1, k0 + 32)              // prefetch next K-tile
            __builtin_amdgcn_sched_barrier(0);     // keep issue above compute
        }
        bf16x8 af[TM], bfr[4];
        #pragma unroll
        for (int i = 0; i < TM; i++) {
            int m = wr * (BM / 2) + i * 16 + l15;
            af[i] = *(const bf16x8*)(&ldsA[cur][m * 32 + quad * 8]);
        }
        #pragma unroll
        for (int j = 0; j < 4; j++) {
            int n = wc * 64 + j * 16 + l15;
            bfr[j] = *(const bf16x8*)(&ldsB[cur][n * 32 + quad * 8]);
        }
        #pragma unroll
        for (int i = 0; i < TM; i++)
            #pragma unroll
            for (int j = 0; j < 4; j++)
                acc[i][j] = __builtin_amdgcn_mfma_f32_16x16x32_bf16(af[i], bfr[j], acc[i][j], 0, 0, 0);
        __syncthreads();                           // buf^1 staged + all reads done
        cur ^= 1;
    }
    // ---- C write (fp8 for layer1, bf16 for layer2) ----
    #pragma unroll
    for (int i = 0; i < TM; i++) {
        #pragma unroll
        for (int j = 0; j < 4; j++) {
            #pragma unroll
            for (int r = 0; r < 4; r++) {
                int row = row0 + wr * (BM / 2) + i * 16 + quad * 4 + r;
                int col = col0 + wc * 64 + j * 16 + l15;
                if (row < M) {
                    float v = acc[i][j][r];
                    if (OMODE == 1)
                        ((u16*)C)[(size_t)row * N + col] = f2bf(v);
                    else
                        ((u8*)C)[(size_t)row * N + col] = f2fp8(v);
                }
            }
        }
    }
    // ---- fused per-row attention dots for this head ----
    float attS_r[4], attD_r[4];
    #pragma unroll
    for (int j = 0; j < 4; j++) {
        int col = wc * 64 + j * 16 + l15;
        attS_r[j] = attS[head * 128 + col];
        attD_r[j] = attD[head * 128 + col];
    }
    #pragma unroll
    for (int i = 0; i < TM; i++) {
        #pragma unroll
        for (int r = 0; r < 4; r++) {
            float ps = 0.f, pd = 0.f;
            #pragma unroll
            for (int j = 0; j < 4; j++) {
                float v = acc[i][j][r];
                ps = fmaf(v, attS_r[j], ps);
                pd = fmaf(v, attD_r[j], pd);
            }
            #pragma unroll
            for (int o = 1; o < 16; o <<= 1) {
                ps += __shfl_xor(ps, o, 64);
                pd += __shfl_xor(pd, o, 64);
            }
            if (l15 == 0) {
                int row = wr * (BM / 2) + i * 16 + quad * 4 + r;
                atomicAdd(&asb[row], ps);
                atomicAdd(&adb[row], pd);
            }
        }
    }
    __syncthreads();
    for (int t = tid; t < BM; t += 256) {
        int row = row0 + t;
        if (row < M) {
            as_out[(size_t)row * NHo + head] = asb[t];
            ad_out[(size_t)row * NHo + head] = adb[t];
        }
    }
}

// ---------- layer-1 softmax-aggregate + ELU, CHANNEL-SLICED, lean PROC ----------
// 8 slices x 128 ch, slice==head, XCD-pinned via blockIdx&7 (R5: FETCH
// 157->53MB proved L2-residency works). R5's regression was VALU-issue
// (89% busy): ~8-9 VALU/edge. This version strips per-edge work to the
// floor:
//  - pl masked ONCE at setup (lane<deg ? exp : 0); pad edges contribute
//    pp=0 automatically -> no per-edge cndmask.
//  - den = bred_sum(pl) hoisted out of the loop -> no per-edge den add.
//  - scalar fmaf(pp, f, a) keeps pp in the SGPR readlane wrote (1 SGPR
//    read per VALU op allowed) -> no pv2 pack movs.
//  - index clamps are SALU (free pipe).
// Per edge: FETCH = readlane + 2B load; PROC = readlane + cvt_pk + 2 fmac.
#define A1_FETCH8(E0, Q)                                                      \
    {                                                                         \
        _Pragma("unroll")                                                     \
        for (int u = 0; u < 8; u++) {                                         \
            int s = __builtin_amdgcn_readlane(idx, (E0) + u);                 \
            s = s < 0 ? 0 : (s > NN - 1 ? NN - 1 : s);   /* SALU clamp */     \
            Q[u] = *(const u16*)(h1q + (size_t)s * D1 + coff);                \
        }                                                                     \
        __builtin_amdgcn_sched_barrier(0);                                    \
    }
#define A1_PROC8(E0, Q)                                                       \
    {                                                                         \
        _Pragma("unroll")                                                     \
        for (int u = 0; u < 8; u++) {                                         \
            float pp = __uint_as_float(__builtin_amdgcn_readlane(             \
                __float_as_uint(pl), (E0) + u));                              \
            f32x2 f = __builtin_amdgcn_cvt_pk_f32_fp8((unsigned int)(Q)[u],   \
                                                      false);                 \
            a0 = fmaf(pp, f[0], a0);                                          \
            a1 = fmaf(pp, f[1], a1);                                          \
        }                                                                     \
    }

__global__ __launch_bounds__(256) void agg1_kernel(const u8* __restrict__ h1q,
                                                   const float* __restrict__ as1,
                                                   const float* __restrict__ ad1,
                                                   const int* __restrict__ cnt,
                                                   const int* __restrict__ csr,
                                                   const float* __restrict__ bias1,
                                                   u16* __restrict__ x2) {
    const int tid = threadIdx.x;
    const int lane = tid & 63;
    const int sl = blockIdx.x & 7;                  // slice == head, XCD-pinned
    const int dst = ((blockIdx.x >> 3) << 2) +
                    __builtin_amdgcn_readfirstlane(tid >> 6);
    const int base = dst * CAP;                     // scalar
    const int coff = sl * 128 + lane * 2;           // 2 channels per lane

    int idx = csr[base + lane];                     // coalesced; || with cnt
    const int deg = max(1, min(cnt[dst], CAP));     // scalar load + SALU
    const float adv = ad1[dst * NH + sl];           // scalar load
    int idxc = idx < 0 ? 0 : (idx > NN - 1 ? NN - 1 : idx);
    float ev = as1[idxc * NH + sl] + adv;           // 640KB L2-resident table
    ev = ev > 0.f ? ev : 0.2f * ev;                 // LeakyReLU(0.2)
    float pl = (lane < deg) ? __expf(ev) : 0.f;     // masked ONCE
    float den = bred_sum(pl);                       // hoisted denominator

    float a0 = 0.f, a1 = 0.f;

    const int nit = (deg + 7) >> 3;                 // groups of 8, ping-pong
    u16 qa[8], qb[8];
    A1_FETCH8(0, qa)
    int g = 0;
    for (; g + 2 < nit; g += 2) {
        A1_FETCH8((g + 1) * 8, qb)
        A1_PROC8(g * 8, qa)
        A1_FETCH8((g + 2) * 8, qa)
        A1_PROC8((g + 1) * 8, qb)
    }
    if (g + 1 < nit) {
        A1_FETCH8((g + 1) * 8, qb)
        A1_PROC8(g * 8, qa)
        A1_PROC8((g + 1) * 8, qb)
    } else {
        A1_PROC8(g * 8, qa)
    }

    float inv = 1.f / (den + 1e-16f);
    float2 bv = *(const float2*)(bias1 + coff);
    a0 = a0 * inv + bv.x;
    a1 = a1 * inv + bv.y;
    a0 = a0 > 0.f ? a0 : (__expf(a0) - 1.f);        // ELU (abs err ~1e-7, tol .03)
    a1 = a1 > 0.f ? a1 : (__expf(a1) - 1.f);
    unsigned int ow = (unsigned int)f2bf(a0) | ((unsigned int)f2bf(a1) << 16);
    *(unsigned int*)(x2 + (size_t)dst * D1 + coff) = ow;
}

// ---------- layer-2 softmax-aggregate + log_softmax, lean PROC ----------
// ONE WAVE per dst; same hoisted-den / pre-masked-pl / scalar-fmaf
// structure as agg1.
#define A2_FETCH8(E0, Q)                                                      \
    {                                                                         \
        _Pragma("unroll")                                                     \
        for (int u = 0; u < 8; u++) {                                         \
            int s = __builtin_amdgcn_readlane(idx, (E0) + u);                 \
            s = s < 0 ? 0 : (s > NN - 1 ? NN - 1 : s);                        \
            Q[u] = *(const unsigned int*)(h2 + (size_t)s * C2 + lane2);       \
        }                                                                     \
        __builtin_amdgcn_sched_barrier(0);                                    \
    }
#define A2_PROC8(E0, Q)                                                       \
    {                                                                         \
        _Pragma("unroll")                                                     \
        for (int u = 0; u < 8; u++) {                                         \
            float pp = __uint_as_float(__builtin_amdgcn_readlane(             \
                __float_as_uint(pl), (E0) + u));                              \
            float f0 = __uint_as_float((Q)[u] << 16);                         \
            float f1 = __uint_as_float((Q)[u] & 0xFFFF0000u);                 \
            a0 = fmaf(pp, f0, a0);                                            \
            a1 = fmaf(pp, f1, a1);                                            \
        }                                                                     \
    }

__global__ __launch_bounds__(256) void agg2_kernel(const u16* __restrict__ h2,
                                                   const float* __restrict__ as2,
                                                   const float* __restrict__ ad2,
                                                   const int* __restrict__ cnt,
                                                   const int* __restrict__ csr,
                                                   const float* __restrict__ bias2,
                                                   float* __restrict__ out) {
    const int tid = threadIdx.x;
    const int lane = tid & 63;
    const int dst = (blockIdx.x << 2) + __builtin_amdgcn_readfirstlane(tid >> 6);
    const int base = dst * CAP;
    const int lane2 = lane * 2;

    int idx = csr[base + lane];                 // coalesced; || with cnt
    const int deg = max(1, min(cnt[dst], CAP)); // scalar
    const float adv = ad2[dst];
    int idxc = idx < 0 ? 0 : (idx > NN - 1 ? NN - 1 : idx);
    float ev = as2[idxc] + adv;                 // random 4B within 80 KB (L2)
    ev = ev > 0.f ? ev : 0.2f * ev;
    float pl = (lane < deg) ? __expf(ev) : 0.f; // masked ONCE
    float den = bred_sum(pl);                   // hoisted

    float a0 = 0.f, a1 = 0.f;

    const int nit = (deg + 7) >> 3;
    unsigned int qa[8], qb[8];
    A2_FETCH8(0, qa)
    int g = 0;
    for (; g + 2 < nit; g += 2) {
        A2_FETCH8((g + 1) * 8, qb)
        A2_PROC8(g * 8, qa)
        A2_FETCH8((g + 2) * 8, qa)
        A2_PROC8((g + 1) * 8, qb)
    }
    if (g + 1 < nit) {
        A2_FETCH8((g + 1) * 8, qb)
        A2_PROC8(g * 8, qa)
        A2_PROC8((g + 1) * 8, qb)
    } else {
        A2_PROC8(g * 8, qa)
    }

    float inv = 1.f / (den + 1e-16f);
    float l0 = a0 * inv + bias2[lane2];
    float l1 = a1 * inv + bias2[lane2 + 1];
    // log_softmax over the wave's 128 channels
    float m = bred_max(fmaxf(l0, l1));
    float ex = bred_sum(__expf(l0 - m) + __expf(l1 - m));
    float lse = m + __logf(ex);
    float2 ov = {l0 - lse, l1 - lse};
    *(float2*)(out + (size_t)dst * C2 + lane2) = ov;
}

extern "C" void kernel_launch(void* const* d_in, const int* in_sizes, int n_in,
                              void* d_out, int out_size, void* d_ws, size_t ws_size,
                              hipStream_t stream) {
    const float* x        = (const float*)d_in[0];
    const int*   ei       = (const int*)d_in[1];
    const float* W1       = (const float*)d_in[2];
    const float* att_src1 = (const float*)d_in[3];
    const float* att_dst1 = (const float*)d_in[4];
    const float* bias1    = (const float*)d_in[5];
    const float* W2       = (const float*)d_in[6];
    const float* att_src2 = (const float*)d_in[7];
    const float* att_dst2 = (const float*)d_in[8];
    const float* bias2    = (const float*)d_in[9];
    float* out = (float*)d_out;
    const int E = in_sizes[1] / 2;

    char* ws = (char*)d_ws;
    size_t off = 0;
    auto alloc = [&](size_t b) {
        void* p = ws + off;
        off += (b + 255) & ~(size_t)255;
        return p;
    };
    u8*  h1q  = (u8*)alloc((size_t)NN * D1);
    u16* x2   = (u16*)alloc((size_t)NN * D1 * 2);
    u16* h2   = (u16*)alloc((size_t)NN * C2 * 2);
    u16* xb   = (u16*)alloc((size_t)NN * FIN * 2);
    u16* w1t  = (u16*)alloc((size_t)D1 * FIN * 2);
    u16* w2t  = (u16*)alloc((size_t)C2 * D1 * 2);
    float* as1 = (float*)alloc((size_t)NN * NH * 4);
    float* ad1 = (float*)alloc((size_t)NN * NH * 4);
    float* as2 = (float*)alloc((size_t)NN * 4);
    float* ad2 = (float*)alloc((size_t)NN * 4);
    int* cnt  = (int*)alloc((size_t)NN * 4);
    int* csr  = (int*)alloc((size_t)NN * CAP * 4);

    // zero cnt up front; fused prep then casts x, transposes W1/W2 AND
    // fills the CSR buckets (fill overlaps the BW-heavy cast blocks)
    hipMemsetAsync(cnt, 0, (size_t)NN * 4, stream);
    const int FILL_BLOCKS = (E + NN + 255) / 256;
    prep_kernel<<<5384 + FILL_BLOCKS, 256, 0, stream>>>(x, xb, W1, w1t, W2, w2t,
                                                        ei, E, cnt, csr);

    // layer 1 GEMM: h1q fp8 + fused per-head as1/ad1
    gemm_mfma<128, 2><<<dim3((NN + 127) / 128, D1 / 128), 256, 0, stream>>>(
        xb, w1t, h1q, att_src1, att_dst1, as1, ad1, NH, NN, D1, FIN);
    // channel-sliced aggregate: 8 slices x 5000 dst-groups
    agg1_kernel<<<((NN + 3) / 4) * 8, 256, 0, stream>>>(h1q, as1, ad1, cnt, csr,
                                                        bias1, x2);
    // layer 2 GEMM: h2 bf16 + fused as2/ad2
    gemm_mfma<64, 1><<<dim3((NN + 63) / 64, C2 / 128), 256, 0, stream>>>(
        x2, w2t, h2, att_src2, att_dst2, as2, ad2, 1, NN, C2, D1);
    agg2_kernel<<<(NN + 3) / 4, 256, 0, stream>>>(h2, as2, ad2, cnt, csr, bias2, out);
}

// Round 7
// 229.950 us; speedup vs baseline: 1.1307x; 1.1254x over previous
//
#include <hip/hip_runtime.h>

#define NN 20000      // nodes
#define FIN 256
#define D1 1024       // H1*C1 = 8*128
#define NH 8
#define C2 128
#define CAP 64        // padded CSR bucket capacity (max degree ~35 incl. self-loop)

typedef unsigned short u16;
typedef unsigned char u8;
typedef __attribute__((ext_vector_type(8))) short bf16x8;
typedef __attribute__((ext_vector_type(4))) float f32x4;
typedef __attribute__((ext_vector_type(2))) float f32x2;

// ---------- bf16 helpers ----------
__device__ __forceinline__ float bf2f(u16 u) {
    return __uint_as_float(((unsigned int)u) << 16);
}
__device__ __forceinline__ u16 f2bf(float f) {
    unsigned int u = __float_as_uint(f);
    u += 0x7FFFu + ((u >> 16) & 1u);   // round-to-nearest-even
    return (u16)(u >> 16);
}
// ---------- fp8 e4m3 (OCP) helpers via HW converts ----------
__device__ __forceinline__ u8 f2fp8(float v) {
    int q = __builtin_amdgcn_cvt_pk_fp8_f32(v, v, 0, false);
    return (u8)(q & 0xFF);
}

// butterfly reductions: every lane ends with the result
__device__ __forceinline__ float bred_max(float v) {
    #pragma unroll
    for (int o = 32; o > 0; o >>= 1) v = fmaxf(v, __shfl_xor(v, o, 64));
    return v;
}
__device__ __forceinline__ float bred_sum(float v) {
    #pragma unroll
    for (int o = 32; o > 0; o >>= 1) v += __shfl_xor(v, o, 64);
    return v;
}

// async global->LDS, 16B per lane (global_load_lds_dwordx4)
typedef const __attribute__((address_space(1))) unsigned int* as1_u32p;
typedef __attribute__((address_space(3))) unsigned int* as3_u32p;
__device__ __forceinline__ void gload_lds16(const void* g, void* l) {
    __builtin_amdgcn_global_load_lds((as1_u32p)g, (as3_u32p)l, 16, 0, 0);
}

// ---------- fused prep: cast x->bf16 | transpose W1/W2 | CSR fill ----------
// cnt is zeroed by hipMemsetAsync BEFORE this kernel, so the fill part can
// run concurrently with the cast/transpose blocks (disjoint data).
// Block ranges: [0,5000) cast, [5000,5256) W1t, [5256,5384) W2t,
// [5384, 5384+ceil((E+NN)/256)) edge fill.
__global__ __launch_bounds__(256) void prep_kernel(const float* __restrict__ x,
                                                   u16* __restrict__ xb,
                                                   const float* __restrict__ W1,
                                                   u16* __restrict__ w1t,
                                                   const float* __restrict__ W2,
                                                   u16* __restrict__ w2t,
                                                   const int* __restrict__ ei,
                                                   int E,
                                                   int* __restrict__ cnt,
                                                   int* __restrict__ csr) {
    __shared__ float tile[32][33];
    const int b = blockIdx.x, tid = threadIdx.x;
    if (b < 5000) {
        int i = (b * 256 + tid) * 4;
        if (i < NN * FIN) {
            float4 v = *(const float4*)(x + i);
            ushort4 o;
            o.x = f2bf(v.x); o.y = f2bf(v.y); o.z = f2bf(v.z); o.w = f2bf(v.w);
            *(ushort4*)(xb + i) = o;
        }
        return;
    }
    if (b < 5384) {
        const float* in; u16* out; int R, C, bx, by;
        if (b < 5256) {
            int q = b - 5000;                 // W1: [FIN x D1] -> [D1 x FIN]
            in = W1; out = w1t; R = FIN; C = D1;
            bx = (q & 31) * 32; by = (q >> 5) * 32;
        } else {
            int q = b - 5256;                 // W2: [D1 x C2] -> [C2 x D1]
            in = W2; out = w2t; R = D1; C = C2;
            bx = (q & 3) * 32; by = (q >> 2) * 32;
        }
        int tx = tid & 31, ty = tid >> 5;     // 32x8
        #pragma unroll
        for (int i = 0; i < 32; i += 8)
            tile[ty + i][tx] = in[(size_t)(by + ty + i) * C + bx + tx];
        __syncthreads();
        #pragma unroll
        for (int i = 0; i < 32; i += 8)
            out[(size_t)(bx + ty + i) * R + by + tx] = f2bf(tile[tx][ty + i]);
        return;
    }
    // ---- padded-bucket CSR fill (self-loops appended) ----
    int j = (b - 5384) * 256 + tid;
    if (j >= E + NN) return;
    int s, d;
    if (j < E) { s = ei[j]; d = ei[E + j]; }
    else { s = j - E; d = j - E; }
    int pos = atomicAdd(&cnt[d], 1);
    if (pos >= CAP) return;   // safety net (never expected)
    csr[d * CAP + pos] = s;
}

// ---------- bf16 MFMA GEMM, 2-phase double-buffered (T3-minimum) ----------
// C[MxN] = A[MxK] * Bt[NxK]^T.  Per K-step: issue next tile's
// global_load_lds into buf^1, then ds_read+MFMA on buf, then ONE
// __syncthreads. Fused per-head attention-dot epilogue.
// OMODE 1: bf16 C out (layer 2); OMODE 2: fp8 e4m3 C out (layer 1).
#define G_STAGE(BUF, K0)                                                   \
    {                                                                      \
        _Pragma("unroll")                                                  \
        for (int i = 0; i < BM / 64; i++) {                                \
            int c = tid + i * 256;                                         \
            int r = c >> 2, ko = (c & 3) * 8;                              \
            int gr = row0 + r; if (gr >= M) gr = M - 1;                    \
            gload_lds16(A + (size_t)gr * K + (K0) + ko,                    \
                        &ldsA[BUF][c * 8]);                                \
        }                                                                  \
        _Pragma("unroll")                                                  \
        for (int i = 0; i < 2; i++) {                                      \
            int c = tid + i * 256;                                         \
            int n = c >> 2, ko = (c & 3) * 8;                              \
            gload_lds16(Bt + (size_t)(col0 + n) * K + (K0) + ko,           \
                        &ldsB[BUF][c * 8]);                                \
        }                                                                  \
    }

template <int BM, int OMODE>
__global__ __launch_bounds__(256) void gemm_mfma(const u16* __restrict__ A,
                                                 const u16* __restrict__ Bt,
                                                 void* __restrict__ C,
                                                 const float* __restrict__ attS,
                                                 const float* __restrict__ attD,
                                                 float* __restrict__ as_out,
                                                 float* __restrict__ ad_out,
                                                 int NHo,
                                                 int M, int N, int K) {
    constexpr int TM = BM / 32;            // 16-tiles per wave along m
    __shared__ u16 ldsA[2][BM * 32];
    __shared__ u16 ldsB[2][128 * 32];
    __shared__ float asb[BM], adb[BM];
    const int tid = threadIdx.x;
    const int lane = tid & 63, w = tid >> 6;
    const int wr = w >> 1, wc = w & 1;
    const int row0 = blockIdx.x * BM, col0 = blockIdx.y * 128;
    const int head = blockIdx.y;
    const int l15 = lane & 15, quad = lane >> 4;

    for (int t = tid; t < BM; t += 256) { asb[t] = 0.f; adb[t] = 0.f; }

    f32x4 acc[TM][4];
    #pragma unroll
    for (int i = 0; i < TM; i++)
        #pragma unroll
        for (int j = 0; j < 4; j++)
            acc[i][j] = (f32x4){0.f, 0.f, 0.f, 0.f};

    G_STAGE(0, 0)
    __syncthreads();
    int cur = 0;
    for (int k0 = 0; k0 < K; k0 += 32) {
        if (k0 + 32 < K) {
            G_STAGE(cur ^ 1, k0 + 32)              // prefetch next K-tile
            __builtin_amdgcn_sched_barrier(0);     // keep issue above compute
        }
        bf16x8 af[TM], bfr[4];
        #pragma unroll
        for (int i = 0; i < TM; i++) {
            int m = wr * (BM / 2) + i * 16 + l15;
            af[i] = *(const bf16x8*)(&ldsA[cur][m * 32 + quad * 8]);
        }
        #pragma unroll
        for (int j = 0; j < 4; j++) {
            int n = wc * 64 + j * 16 + l15;
            bfr[j] = *(const bf16x8*)(&ldsB[cur][n * 32 + quad * 8]);
        }
        #pragma unroll
        for (int i = 0; i < TM; i++)
            #pragma unroll
            for (int j = 0; j < 4; j++)
                acc[i][j] = __builtin_amdgcn_mfma_f32_16x16x32_bf16(af[i], bfr[j], acc[i][j], 0, 0, 0);
        __syncthreads();                           // buf^1 staged + all reads done
        cur ^= 1;
    }
    // ---- C write (fp8 for layer1, bf16 for layer2) ----
    #pragma unroll
    for (int i = 0; i < TM; i++) {
        #pragma unroll
        for (int j = 0; j < 4; j++) {
            #pragma unroll
            for (int r = 0; r < 4; r++) {
                int row = row0 + wr * (BM / 2) + i * 16 + quad * 4 + r;
                int col = col0 + wc * 64 + j * 16 + l15;
                if (row < M) {
                    float v = acc[i][j][r];
                    if (OMODE == 1)
                        ((u16*)C)[(size_t)row * N + col] = f2bf(v);
                    else
                        ((u8*)C)[(size_t)row * N + col] = f2fp8(v);
                }
            }
        }
    }
    // ---- fused per-row attention dots for this head ----
    float attS_r[4], attD_r[4];
    #pragma unroll
    for (int j = 0; j < 4; j++) {
        int col = wc * 64 + j * 16 + l15;
        attS_r[j] = attS[head * 128 + col];
        attD_r[j] = attD[head * 128 + col];
    }
    #pragma unroll
    for (int i = 0; i < TM; i++) {
        #pragma unroll
        for (int r = 0; r < 4; r++) {
            float ps = 0.f, pd = 0.f;
            #pragma unroll
            for (int j = 0; j < 4; j++) {
                float v = acc[i][j][r];
                ps = fmaf(v, attS_r[j], ps);
                pd = fmaf(v, attD_r[j], pd);
            }
            #pragma unroll
            for (int o = 1; o < 16; o <<= 1) {
                ps += __shfl_xor(ps, o, 64);
                pd += __shfl_xor(pd, o, 64);
            }
            if (l15 == 0) {
                int row = wr * (BM / 2) + i * 16 + quad * 4 + r;
                atomicAdd(&asb[row], ps);
                atomicAdd(&adb[row], pd);
            }
        }
    }
    __syncthreads();
    for (int t = tid; t < BM; t += 256) {
        int row = row0 + t;
        if (row < M) {
            as_out[(size_t)row * NHo + head] = asb[t];
            ad_out[(size_t)row * NHo + head] = adb[t];
        }
    }
}

// ---------- layer-1 softmax-aggregate + ELU (WIDE, R4 structure) ----------
// ONE WAVE per dst, 16 ch/lane covering all 1024 ch; GROUP=8 depth-2
// ping-pong; inline per-edge as1 weight load (L2-resident 640KB table).
// Measured R4: 55.2us at 3.67TB/s fabric = the wide structure's BW floor.
// (Sliced L2-resident variants R5/R6 measured 88-92us: issue-bound at
// 8x per-edge overhead. Wide fabric-bound < sliced issue-bound.)
#define A1_FETCH8(E0, Q, P)                                                   \
    {                                                                         \
        _Pragma("unroll")                                                     \
        for (int u = 0; u < 8; u++) {                                         \
            int e = (E0) + u;             /* e <= 63 < CAP always */          \
            int s = __builtin_amdgcn_readlane(idx, e);                        \
            s = s < 0 ? 0 : (s > NN - 1 ? NN - 1 : s);   /* SALU clamp */     \
            Q[u] = *(const uint4*)(h1q + (size_t)s * D1 + c0);                \
            P[u] = as1[s * NH + h];       /* L2-hit 4B; masked at PROC */     \
        }                                                                     \
        __builtin_amdgcn_sched_barrier(0);                                    \
    }
#define A1_PROC8(E0, Q, P)                                                    \
    {                                                                         \
        _Pragma("unroll")                                                     \
        for (int u = 0; u < 8; u++) {                                         \
            float ev = (P)[u] + adv;                                          \
            ev = ev > 0.f ? ev : 0.2f * ev;           /* LeakyReLU(0.2) */    \
            float pp = ((E0) + u < deg) ? __expf(ev) : 0.f;                   \
            den += pp;                                                        \
            f32x2 pv2 = {pp, pp};                                             \
            acc[0] += pv2 * __builtin_amdgcn_cvt_pk_f32_fp8((Q)[u].x, false); \
            acc[1] += pv2 * __builtin_amdgcn_cvt_pk_f32_fp8((Q)[u].x, true);  \
            acc[2] += pv2 * __builtin_amdgcn_cvt_pk_f32_fp8((Q)[u].y, false); \
            acc[3] += pv2 * __builtin_amdgcn_cvt_pk_f32_fp8((Q)[u].y, true);  \
            acc[4] += pv2 * __builtin_amdgcn_cvt_pk_f32_fp8((Q)[u].z, false); \
            acc[5] += pv2 * __builtin_amdgcn_cvt_pk_f32_fp8((Q)[u].z, true);  \
            acc[6] += pv2 * __builtin_amdgcn_cvt_pk_f32_fp8((Q)[u].w, false); \
            acc[7] += pv2 * __builtin_amdgcn_cvt_pk_f32_fp8((Q)[u].w, true);  \
        }                                                                     \
    }

__global__ __launch_bounds__(256) void agg1_kernel(const u8* __restrict__ h1q,
                                                   const float* __restrict__ as1,
                                                   const float* __restrict__ ad1,
                                                   const int* __restrict__ cnt,
                                                   const int* __restrict__ csr,
                                                   const float* __restrict__ bias1,
                                                   u16* __restrict__ x2) {
    const int tid = threadIdx.x;
    const int lane = tid & 63;
    const int dst = (blockIdx.x << 2) + (tid >> 6);
    const int c0 = lane * 16;               // 16 channels per lane
    const int h = lane >> 3;                // head (all 16 lane-channels same head)
    const int base = dst * CAP;

    int idx = csr[base + lane];                     // unclamped: || with cnt load
    const int deg = __builtin_amdgcn_readfirstlane(max(1, min(cnt[dst], CAP)));
    const float adv = ad1[dst * NH + h];            // per-head dst term

    f32x2 acc[8];
    #pragma unroll
    for (int k = 0; k < 8; k++) acc[k] = (f32x2){0.f, 0.f};
    float den = 0.f;

    const int nit = (deg + 7) >> 3;                 // groups of 8
    uint4 qa[8], qb[8];
    float pa[8], pb[8];
    A1_FETCH8(0, qa, pa)
    int g = 0;
    for (; g + 2 < nit; g += 2) {                   // ping-pong
        A1_FETCH8((g + 1) * 8, qb, pb)
        A1_PROC8(g * 8, qa, pa)
        A1_FETCH8((g + 2) * 8, qa, pa)
        A1_PROC8((g + 1) * 8, qb, pb)
    }
    if (g + 1 < nit) {
        A1_FETCH8((g + 1) * 8, qb, pb)
        A1_PROC8(g * 8, qa, pa)
        A1_PROC8((g + 1) * 8, qb, pb)
    } else {
        A1_PROC8(g * 8, qa, pa)
    }

    float inv = 1.f / (den + 1e-16f);
    u16 ov[16];
    #pragma unroll
    for (int k = 0; k < 8; k++) {
        float a0 = acc[k][0] * inv + bias1[c0 + 2 * k];
        float a1 = acc[k][1] * inv + bias1[c0 + 2 * k + 1];
        a0 = a0 > 0.f ? a0 : (__expf(a0) - 1.f);   // ELU (abs err ~1e-7, tol 0.03)
        a1 = a1 > 0.f ? a1 : (__expf(a1) - 1.f);
        ov[2 * k] = f2bf(a0);
        ov[2 * k + 1] = f2bf(a1);
    }
    *(uint4*)(x2 + (size_t)dst * D1 + c0) = *(const uint4*)ov;
    *(uint4*)(x2 + (size_t)dst * D1 + c0 + 8) = *(const uint4*)(ov + 8);
}

// ---------- layer-2 softmax-aggregate + log_softmax, lean PROC (R6) ----------
// ONE WAVE per dst; hoisted den / pre-masked pl / scalar-fmaf.
#define A2_FETCH8(E0, Q)                                                      \
    {                                                                         \
        _Pragma("unroll")                                                     \
        for (int u = 0; u < 8; u++) {                                         \
            int s = __builtin_amdgcn_readlane(idx, (E0) + u);                 \
            s = s < 0 ? 0 : (s > NN - 1 ? NN - 1 : s);                        \
            Q[u] = *(const unsigned int*)(h2 + (size_t)s * C2 + lane2);       \
        }                                                                     \
        __builtin_amdgcn_sched_barrier(0);                                    \
    }
#define A2_PROC8(E0, Q)                                                       \
    {                                                                         \
        _Pragma("unroll")                                                     \
        for (int u = 0; u < 8; u++) {                                         \
            float pp = __uint_as_float(__builtin_amdgcn_readlane(             \
                __float_as_uint(pl), (E0) + u));                              \
            float f0 = __uint_as_float((Q)[u] << 16);                         \
            float f1 = __uint_as_float((Q)[u] & 0xFFFF0000u);                 \
            a0 = fmaf(pp, f0, a0);                                            \
            a1 = fmaf(pp, f1, a1);                                            \
        }                                                                     \
    }

__global__ __launch_bounds__(256) void agg2_kernel(const u16* __restrict__ h2,
                                                   const float* __restrict__ as2,
                                                   const float* __restrict__ ad2,
                                                   const int* __restrict__ cnt,
                                                   const int* __restrict__ csr,
                                                   const float* __restrict__ bias2,
                                                   float* __restrict__ out) {
    const int tid = threadIdx.x;
    const int lane = tid & 63;
    const int dst = (blockIdx.x << 2) + __builtin_amdgcn_readfirstlane(tid >> 6);
    const int base = dst * CAP;
    const int lane2 = lane * 2;

    int idx = csr[base + lane];                 // coalesced; || with cnt
    const int deg = max(1, min(cnt[dst], CAP)); // scalar
    const float adv = ad2[dst];
    int idxc = idx < 0 ? 0 : (idx > NN - 1 ? NN - 1 : idx);
    float ev = as2[idxc] + adv;                 // random 4B within 80 KB (L2)
    ev = ev > 0.f ? ev : 0.2f * ev;
    float pl = (lane < deg) ? __expf(ev) : 0.f; // masked ONCE
    float den = bred_sum(pl);                   // hoisted

    float a0 = 0.f, a1 = 0.f;

    const int nit = (deg + 7) >> 3;
    unsigned int qa[8], qb[8];
    A2_FETCH8(0, qa)
    int g = 0;
    for (; g + 2 < nit; g += 2) {
        A2_FETCH8((g + 1) * 8, qb)
        A2_PROC8(g * 8, qa)
        A2_FETCH8((g + 2) * 8, qa)
        A2_PROC8((g + 1) * 8, qb)
    }
    if (g + 1 < nit) {
        A2_FETCH8((g + 1) * 8, qb)
        A2_PROC8(g * 8, qa)
        A2_PROC8((g + 1) * 8, qb)
    } else {
        A2_PROC8(g * 8, qa)
    }

    float inv = 1.f / (den + 1e-16f);
    float l0 = a0 * inv + bias2[lane2];
    float l1 = a1 * inv + bias2[lane2 + 1];
    // log_softmax over the wave's 128 channels
    float m = bred_max(fmaxf(l0, l1));
    float ex = bred_sum(__expf(l0 - m) + __expf(l1 - m));
    float lse = m + __logf(ex);
    float2 ov = {l0 - lse, l1 - lse};
    *(float2*)(out + (size_t)dst * C2 + lane2) = ov;
}

extern "C" void kernel_launch(void* const* d_in, const int* in_sizes, int n_in,
                              void* d_out, int out_size, void* d_ws, size_t ws_size,
                              hipStream_t stream) {
    const float* x        = (const float*)d_in[0];
    const int*   ei       = (const int*)d_in[1];
    const float* W1       = (const float*)d_in[2];
    const float* att_src1 = (const float*)d_in[3];
    const float* att_dst1 = (const float*)d_in[4];
    const float* bias1    = (const float*)d_in[5];
    const float* W2       = (const float*)d_in[6];
    const float* att_src2 = (const float*)d_in[7];
    const float* att_dst2 = (const float*)d_in[8];
    const float* bias2    = (const float*)d_in[9];
    float* out = (float*)d_out;
    const int E = in_sizes[1] / 2;

    char* ws = (char*)d_ws;
    size_t off = 0;
    auto alloc = [&](size_t b) {
        void* p = ws + off;
        off += (b + 255) & ~(size_t)255;
        return p;
    };
    u8*  h1q  = (u8*)alloc((size_t)NN * D1);
    u16* x2   = (u16*)alloc((size_t)NN * D1 * 2);
    u16* h2   = (u16*)alloc((size_t)NN * C2 * 2);
    u16* xb   = (u16*)alloc((size_t)NN * FIN * 2);
    u16* w1t  = (u16*)alloc((size_t)D1 * FIN * 2);
    u16* w2t  = (u16*)alloc((size_t)C2 * D1 * 2);
    float* as1 = (float*)alloc((size_t)NN * NH * 4);
    float* ad1 = (float*)alloc((size_t)NN * NH * 4);
    float* as2 = (float*)alloc((size_t)NN * 4);
    float* ad2 = (float*)alloc((size_t)NN * 4);
    int* cnt  = (int*)alloc((size_t)NN * 4);
    int* csr  = (int*)alloc((size_t)NN * CAP * 4);

    // zero cnt up front; fused prep then casts x, transposes W1/W2 AND
    // fills the CSR buckets (fill overlaps the BW-heavy cast blocks)
    hipMemsetAsync(cnt, 0, (size_t)NN * 4, stream);
    const int FILL_BLOCKS = (E + NN + 255) / 256;
    prep_kernel<<<5384 + FILL_BLOCKS, 256, 0, stream>>>(x, xb, W1, w1t, W2, w2t,
                                                        ei, E, cnt, csr);

    // layer 1 GEMM: h1q fp8 + fused per-head as1/ad1
    gemm_mfma<128, 2><<<dim3((NN + 127) / 128, D1 / 128), 256, 0, stream>>>(
        xb, w1t, h1q, att_src1, att_dst1, as1, ad1, NH, NN, D1, FIN);
    // 1 wave per dst: 20000 waves = 5000 blocks
    agg1_kernel<<<(NN + 3) / 4, 256, 0, stream>>>(h1q, as1, ad1, cnt, csr,
                                                  bias1, x2);
    // layer 2 GEMM: h2 bf16 + fused as2/ad2
    gemm_mfma<64, 1><<<dim3((NN + 63) / 64, C2 / 128), 256, 0, stream>>>(
        x2, w2t, h2, att_src2, att_dst2, as2, ad2, 1, NN, C2, D1);
    agg2_kernel<<<(NN + 3) / 4, 256, 0, stream>>>(h2, as2, ad2, cnt, csr, bias2, out);
}